// Round 3
// baseline (380.453 us; speedup 1.0000x reference)
//
#include <hip/hip_runtime.h>

#define NUM_CODES 512
#define DIM 64
#define NPIX (32 * 64 * 64)  // 131072 pixels
#define CT (NUM_CODES / 16)  // 32 code tiles of 16 codes
#define BLK 64               // ONE wave per block: no barriers, no LDS
#define PPB 16               // pixels per block = 16 (one MFMA pixel tile)

typedef __attribute__((ext_vector_type(8))) short bf16x8;
typedef __attribute__((ext_vector_type(4))) float f32x4;

__device__ __forceinline__ unsigned short f2bf(float f) {
    unsigned u = __float_as_uint(f);
    return (unsigned short)((u + 0x7fffu + ((u >> 16) & 1u)) >> 16);
}
__device__ __forceinline__ float bf2f(unsigned short h) {
    return __uint_as_float(((unsigned)h) << 16);
}

// ---------------------------------------------------------------------------
// Prep: swizzle NEGATED codebook into bf16 hi/lo A-fragment order + exact
// l2e + l2e/2. A-frag (16x16x32): lane = (k_in_32/8)*16 + m, elem j = k%8.
// With -e in A and acc initialized to l2e/2, the MFMA output IS the
// selection key  l2e/2 - dot  directly.
// ---------------------------------------------------------------------------
__global__ __launch_bounds__(256) void prep_kernel(
    const float* __restrict__ emb, unsigned short* __restrict__ AH,
    unsigned short* __restrict__ ALO, float* __restrict__ l2e,
    float* __restrict__ l2eh) {
    const int t = blockIdx.x * 256 + threadIdx.x;  // 0..8191
    const int e0 = t * 4;
    const int c = e0 >> 6, d0 = e0 & 63;
    const float4 v = *(const float4*)(emb + c * DIM + d0);
    float f[4] = {-v.x, -v.y, -v.z, -v.w};  // NEGATED
    unsigned short h[4], l[4];
#pragma unroll
    for (int i = 0; i < 4; ++i) {
        h[i] = f2bf(f[i]);
        l[i] = f2bf(f[i] - bf2f(h[i]));
    }
    const int ct = c >> 4, mr = c & 15, s = d0 >> 5, q = (d0 & 31) >> 3,
              j0 = d0 & 7;
    const int base = ((ct * 2 + s) * 64 + (q * 16 + mr)) * 8 + j0;
    *(ushort4*)(AH + base) = make_ushort4(h[0], h[1], h[2], h[3]);
    *(ushort4*)(ALO + base) = make_ushort4(l[0], l[1], l[2], l[3]);

    if (t < NUM_CODES) {  // exact ||e||^2, validated pairwise-8 order
        const float* e = emb + t * DIM;
        float r[8];
#pragma unroll
        for (int j = 0; j < 8; ++j) {
            float w = e[j];
            r[j] = w * w;
        }
#pragma unroll
        for (int i = 8; i < DIM; i += 8)
#pragma unroll
            for (int j = 0; j < 8; ++j) {
                float w = e[i + j];
                r[j] += w * w;
            }
        float sv =
            ((r[0] + r[1]) + (r[2] + r[3])) + ((r[4] + r[5]) + (r[6] + r[7]));
        l2e[t] = sv;
        l2eh[t] = 0.5f * sv;
    }
}

// ---------------------------------------------------------------------------
// Main: ONE wave per block, 16 px/wave, grid 8192 -> 32 blocks/CU ->
// 8 waves/SIMD (2x R2). Zero LDS, zero barriers: acc-init from global
// l2eh (2-deep prefetched like the fragments), top-2 candidates passed
// via __shfl, refine reads l2e[] directly. Validated arithmetic orders
// preserved exactly (pairwise-8 l2x, strict-serial dot, med3 insert,
// lexicographic (d,k) refine winner).
// ---------------------------------------------------------------------------
__global__ __launch_bounds__(BLK, 8) void vq_main(
    const float* __restrict__ x_in, const unsigned short* __restrict__ AH,
    const unsigned short* __restrict__ ALO, const float* __restrict__ l2e,
    const float* __restrict__ l2eh, const float* __restrict__ emb,
    float* __restrict__ codes_out, float* __restrict__ vecs_out) {
    const int lane = threadIdx.x;  // 64 threads = 1 wave
    const int p = lane & 15, q = lane >> 4;
    const int pw = blockIdx.x * PPB;

    // ---- B fragments: B[k][n]: n=lane&15 (pixel), k=(lane>>4)*8+j ----
    bf16x8 bh0, bl0, bh1, bl1;
    {
        const float* xb = x_in + (size_t)(pw + p) * DIM + q * 8;
        float4 u0 = *(const float4*)(xb);
        float4 u1 = *(const float4*)(xb + 4);
        float4 u2 = *(const float4*)(xb + 32);
        float4 u3 = *(const float4*)(xb + 36);
        float f0[8] = {u0.x, u0.y, u0.z, u0.w, u1.x, u1.y, u1.z, u1.w};
        float f1[8] = {u2.x, u2.y, u2.z, u2.w, u3.x, u3.y, u3.z, u3.w};
#pragma unroll
        for (int j = 0; j < 8; ++j) {
            unsigned short hh = f2bf(f0[j]);
            bh0[j] = (short)hh;
            bl0[j] = (short)f2bf(f0[j] - bf2f(hh));
            unsigned short h2 = f2bf(f1[j]);
            bh1[j] = (short)h2;
            bl1[j] = (short)f2bf(f1[j] - bf2f(h2));
        }
    }

    const int rowbase = q * 4;  // C/D: row = (lane>>4)*4 + reg
    float d1 = 3.4e38f, d2 = 3.4e38f;
    int k1 = 0, k2 = 0;

    const unsigned short* pAH = AH + lane * 8;
    const unsigned short* pAL = ALO + lane * 8;
    const float* pL = l2eh + rowbase;  // per-lane acc-init base

    // ---- prime tiles 0 and 1 (2-deep prefetch pipeline) ----
    bf16x8 c0h = *(const bf16x8*)(pAH);
    bf16x8 c0l = *(const bf16x8*)(pAL);
    bf16x8 c1h = *(const bf16x8*)(pAH + 512);
    bf16x8 c1l = *(const bf16x8*)(pAL + 512);
    f32x4 ci = *(const f32x4*)(pL);
    bf16x8 p0h = *(const bf16x8*)(pAH + 1024);
    bf16x8 p0l = *(const bf16x8*)(pAL + 1024);
    bf16x8 p1h = *(const bf16x8*)(pAH + 1024 + 512);
    bf16x8 p1l = *(const bf16x8*)(pAL + 1024 + 512);
    f32x4 pi = *(const f32x4*)(pL + 16);

#pragma unroll 4
    for (int ct = 0; ct < CT; ++ct) {
        // prefetch tile ct+2 (wraps; harmless redundant loads on last iters)
        const int nt = (ct + 2) & (CT - 1);
        const bf16x8 q0h = *(const bf16x8*)(pAH + nt * 1024);
        const bf16x8 q0l = *(const bf16x8*)(pAL + nt * 1024);
        const bf16x8 q1h = *(const bf16x8*)(pAH + nt * 1024 + 512);
        const bf16x8 q1l = *(const bf16x8*)(pAL + nt * 1024 + 512);
        const f32x4 qi = *(const f32x4*)(pL + nt * 16);

        // ---- MFMA cluster: 2 independent 3-chains ----
        __builtin_amdgcn_s_setprio(1);
        f32x4 a = ci;  // l2e/2 pre-init: output IS the key
        a = __builtin_amdgcn_mfma_f32_16x16x32_bf16(c0h, bh0, a, 0, 0, 0);
        a = __builtin_amdgcn_mfma_f32_16x16x32_bf16(c0l, bh0, a, 0, 0, 0);
        a = __builtin_amdgcn_mfma_f32_16x16x32_bf16(c0h, bl0, a, 0, 0, 0);
        f32x4 b = {0.f, 0.f, 0.f, 0.f};
        b = __builtin_amdgcn_mfma_f32_16x16x32_bf16(c1h, bh1, b, 0, 0, 0);
        b = __builtin_amdgcn_mfma_f32_16x16x32_bf16(c1l, bh1, b, 0, 0, 0);
        b = __builtin_amdgcn_mfma_f32_16x16x32_bf16(c1h, bl1, b, 0, 0, 0);
        __builtin_amdgcn_s_setprio(0);

        // ---- top-2 insert (validated med3 form; key = a+b) ----
        const int kb = ct * 16 + rowbase;
#pragma unroll
        for (int r = 0; r < 4; ++r) {
            const float d = a[r] + b[r];  // l2e/2 - dot
            const int kk = kb + r;
            const bool c = d < d1, c2 = d < d2;
            const float nd2 = __builtin_amdgcn_fmed3f(d1, d2, d);
            const int nk2 = c2 ? kk : k2;
            k2 = c ? k1 : nk2;
            k1 = c ? kk : k1;
            d2 = nd2;
            d1 = fminf(d1, d);
        }

        // rotate pipeline regs (renamed away under unroll)
        c0h = p0h; c0l = p0l; c1h = p1h; c1l = p1l; ci = pi;
        p0h = q0h; p0l = q0l; p1h = q1h; p1l = q1l; pi = qi;
    }

    // ---- cross-lane top-2 merge (lanes l, l^16, l^32 share pixel col);
    //      after the butterfly EVERY lane holds the merged result ----
    {
        float a1 = d1, a2 = d2;
        int b1 = k1, b2 = k2;
#pragma unroll
        for (int off = 16; off <= 32; off <<= 1) {
            const float od1 = __shfl_xor(a1, off);
            const int ok1 = __shfl_xor(b1, off);
            const float od2 = __shfl_xor(a2, off);
            const int ok2 = __shfl_xor(b2, off);
            const bool c = od1 < a1;
            const float w1 = c ? od1 : a1;
            const int wk1 = c ? ok1 : b1;
            const float l1 = c ? a1 : od1;
            const int lk1 = c ? b1 : ok1;
            const bool cm = od2 < a2;
            const float m2 = cm ? od2 : a2;
            const int mk2 = cm ? ok2 : b2;
            const bool c3 = m2 < l1;
            a2 = c3 ? m2 : l1;
            b2 = c3 ? mk2 : lk1;
            a1 = w1;
            b1 = wk1;
        }
        d1 = a1; k1 = b1;
        d2 = a2; k2 = b2;
    }

    // ---- exact refine, pair-parallel: lanes 0..31, 2 lanes per pixel,
    //      one candidate each; winner = lexicographic min of (d, k).
    //      One-pass x/e chunk loads; summation orders preserved exactly:
    //      pairwise-8 for l2x (identical on both lanes of a pair, so it
    //      cancels in the compare), strict-serial fma for the dot. ----
    int sel;
    {
        const int pixloc = (lane >> 1) & 15, which = lane & 1;
        // merged top-2 for pixel col pixloc lives in lane pixloc (any copy)
        const int ka = __shfl(k1, pixloc);
        const int kb2 = __shfl(k2, pixloc);
        const int k_me = which ? kb2 : ka;
        float d_me = 3.4e38f;
        if (lane < 32) {
            const int pix = pw + pixloc;
            const float* xr = x_in + (size_t)pix * DIM;
            const float* er = emb + (size_t)k_me * DIM;
            float r[8];
            float acc = 0.f;
#pragma unroll
            for (int i = 0; i < DIM; i += 8) {
                const float4 xa = *(const float4*)(xr + i);
                const float4 xb2 = *(const float4*)(xr + i + 4);
                const float4 ea = *(const float4*)(er + i);
                const float4 eb = *(const float4*)(er + i + 4);
                if (i == 0) {
                    r[0] = xa.x * xa.x; r[1] = xa.y * xa.y;
                    r[2] = xa.z * xa.z; r[3] = xa.w * xa.w;
                    r[4] = xb2.x * xb2.x; r[5] = xb2.y * xb2.y;
                    r[6] = xb2.z * xb2.z; r[7] = xb2.w * xb2.w;
                } else {
                    r[0] += xa.x * xa.x; r[1] += xa.y * xa.y;
                    r[2] += xa.z * xa.z; r[3] += xa.w * xa.w;
                    r[4] += xb2.x * xb2.x; r[5] += xb2.y * xb2.y;
                    r[6] += xb2.z * xb2.z; r[7] += xb2.w * xb2.w;
                }
                acc = __builtin_fmaf(xa.x, ea.x, acc);
                acc = __builtin_fmaf(xa.y, ea.y, acc);
                acc = __builtin_fmaf(xa.z, ea.z, acc);
                acc = __builtin_fmaf(xa.w, ea.w, acc);
                acc = __builtin_fmaf(xb2.x, eb.x, acc);
                acc = __builtin_fmaf(xb2.y, eb.y, acc);
                acc = __builtin_fmaf(xb2.z, eb.z, acc);
                acc = __builtin_fmaf(xb2.w, eb.w, acc);
            }
            const float l2x = ((r[0] + r[1]) + (r[2] + r[3])) +
                              ((r[4] + r[5]) + (r[6] + r[7]));
            d_me = (l2x + l2e[k_me]) - 2.0f * acc;
        }
        const float d_o = __shfl_xor(d_me, 1);
        const int k_o = __shfl_xor(k_me, 1);
        sel = (d_me < d_o || (d_me == d_o && k_me < k_o)) ? k_me : k_o;
        if (lane < 32 && which == 0) {
            codes_out[pw + pixloc] = (float)sel;
        }
    }

    // ---- coalesced gather: 16 px * 16 float4 = 256 float4, 4 iters;
    //      code for pixel pp lives in lane 2*pp (0..30, all valid) ----
    const float4* emb4 = (const float4*)emb;
    float4* vout4 = (float4*)(vecs_out + (size_t)blockIdx.x * PPB * DIM);
#pragma unroll
    for (int it = 0; it < (PPB * DIM / 4) / BLK; ++it) {
        const int fidx = lane + it * BLK;
        const int pp = fidx >> 4, dd = fidx & 15;
        const int cpp = __shfl(sel, pp * 2);
        vout4[fidx] = emb4[(size_t)cpp * (DIM / 4) + dd];
    }
}

extern "C" void kernel_launch(void* const* d_in, const int* in_sizes, int n_in,
                              void* d_out, int out_size, void* d_ws,
                              size_t ws_size, hipStream_t stream) {
    const float* x_in = (const float*)d_in[0];  // [32,64,64,64] fp32
    const float* emb = (const float*)d_in[1];   // [512,64] fp32

    // workspace layout
    unsigned short* AH = (unsigned short*)d_ws;    // 64 KB (negated hi)
    unsigned short* ALO = AH + NUM_CODES * DIM;    // 64 KB (negated lo)
    float* l2e = (float*)(ALO + NUM_CODES * DIM);  // 2 KB
    float* l2eh = l2e + NUM_CODES;                 // 2 KB

    float* codes_out = (float*)d_out;        // NPIX floats (codes as f32)
    float* vecs_out = (float*)d_out + NPIX;  // NPIX*DIM floats

    hipLaunchKernelGGL(prep_kernel, dim3(32), dim3(256), 0, stream, emb, AH,
                       ALO, l2e, l2eh);
    hipLaunchKernelGGL(vq_main, dim3(NPIX / PPB), dim3(BLK), 0, stream, x_in,
                       AH, ALO, l2e, l2eh, emb, codes_out, vecs_out);
}

// Round 4
// 128.925 us; speedup vs baseline: 2.9510x; 2.9510x over previous
//
#include <hip/hip_runtime.h>

#define NUM_CODES 512
#define DIM 64
#define NPIX (32 * 64 * 64)  // 131072 pixels
#define CT (NUM_CODES / 16)  // 32 code tiles of 16 codes
#define BLK 256
#define NGRP 1               // pixel groups per wave (16 px each) -> 16 px/wave
#define PPB 64               // pixels per block = 4 waves * 16 px

typedef __attribute__((ext_vector_type(8))) short bf16x8;
typedef __attribute__((ext_vector_type(4))) float f32x4;

__device__ __forceinline__ unsigned short f2bf(float f) {
    unsigned u = __float_as_uint(f);
    return (unsigned short)((u + 0x7fffu + ((u >> 16) & 1u)) >> 16);
}
__device__ __forceinline__ float bf2f(unsigned short h) {
    return __uint_as_float(((unsigned)h) << 16);
}

// ---------------------------------------------------------------------------
// Prep: swizzle NEGATED codebook into bf16 hi/lo A-fragment order + exact
// l2e + l2e/2. A-frag (16x16x32): lane = (k_in_32/8)*16 + m, elem j = k%8.
// With -e in A and acc initialized to l2e/2, the MFMA output IS the
// selection key  l2e/2 - dot  directly.
// ---------------------------------------------------------------------------
__global__ __launch_bounds__(256) void prep_kernel(
    const float* __restrict__ emb, unsigned short* __restrict__ AH,
    unsigned short* __restrict__ ALO, float* __restrict__ l2e,
    float* __restrict__ l2eh) {
    const int t = blockIdx.x * 256 + threadIdx.x;  // 0..8191
    const int e0 = t * 4;
    const int c = e0 >> 6, d0 = e0 & 63;
    const float4 v = *(const float4*)(emb + c * DIM + d0);
    float f[4] = {-v.x, -v.y, -v.z, -v.w};  // NEGATED
    unsigned short h[4], l[4];
#pragma unroll
    for (int i = 0; i < 4; ++i) {
        h[i] = f2bf(f[i]);
        l[i] = f2bf(f[i] - bf2f(h[i]));
    }
    const int ct = c >> 4, mr = c & 15, s = d0 >> 5, q = (d0 & 31) >> 3,
              j0 = d0 & 7;
    const int base = ((ct * 2 + s) * 64 + (q * 16 + mr)) * 8 + j0;
    *(ushort4*)(AH + base) = make_ushort4(h[0], h[1], h[2], h[3]);
    *(ushort4*)(ALO + base) = make_ushort4(l[0], l[1], l[2], l[3]);

    if (t < NUM_CODES) {  // exact ||e||^2, validated pairwise-8 order
        const float* e = emb + t * DIM;
        float r[8];
#pragma unroll
        for (int j = 0; j < 8; ++j) {
            float w = e[j];
            r[j] = w * w;
        }
#pragma unroll
        for (int i = 8; i < DIM; i += 8)
#pragma unroll
            for (int j = 0; j < 8; ++j) {
                float w = e[i + j];
                r[j] += w * w;
            }
        float sv =
            ((r[0] + r[1]) + (r[2] + r[3])) + ((r[4] + r[5]) + (r[6] + r[7]));
        l2e[t] = sv;
        l2eh[t] = 0.5f * sv;
    }
}

// ---------------------------------------------------------------------------
// Main: 4 waves / 64 px (NGRP=1). Grid 2048 -> 8 blocks/CU: occupancy was
// grid-capped at 4 blocks/CU in R2 (VGPR=64 already allowed 8 waves/SIMD).
// launch_bounds(256,6): cap 85 >> demand, zero spill risk (R3 lesson).
// 1-deep fragment prefetch (TLP at 7-8 waves/SIMD covers L2 latency);
// chain-split 2x3 MFMA (R2-validated); med3 top-2 insert (R1-validated);
// one-pass low-register exact refine (R3-validated numerics), 2 thr/px.
// ---------------------------------------------------------------------------
__global__ __launch_bounds__(BLK, 6) void vq_main(
    const float* __restrict__ x_in, const unsigned short* __restrict__ AH,
    const unsigned short* __restrict__ ALO, const float* __restrict__ l2e,
    const float* __restrict__ l2eh, const float* __restrict__ emb,
    float* __restrict__ codes_out, float* __restrict__ vecs_out) {
    __shared__ float s_l2eh[NUM_CODES];
    __shared__ float s_l2ex[NUM_CODES];
    __shared__ int s_top[PPB][2];
    __shared__ int s_code[PPB];

    const int tid = threadIdx.x, lane = tid & 63, wave = tid >> 6;
    s_l2eh[tid] = l2eh[tid];
    s_l2eh[tid + 256] = l2eh[tid + 256];
    s_l2ex[tid] = l2e[tid];
    s_l2ex[tid + 256] = l2e[tid + 256];
    __syncthreads();

    const int p = lane & 15, q = lane >> 4;
    const int pw = blockIdx.x * PPB + wave * 16;  // wave's 16 px

    // ---- B fragments: B[k][n]: n=lane&15 (pixel), k=(lane>>4)*8+j ----
    bf16x8 bh0, bl0, bh1, bl1;
    {
        const float* xb = x_in + (size_t)(pw + p) * DIM + q * 8;
        float4 u0 = *(const float4*)(xb);
        float4 u1 = *(const float4*)(xb + 4);
        float4 u2 = *(const float4*)(xb + 32);
        float4 u3 = *(const float4*)(xb + 36);
        float f0[8] = {u0.x, u0.y, u0.z, u0.w, u1.x, u1.y, u1.z, u1.w};
        float f1[8] = {u2.x, u2.y, u2.z, u2.w, u3.x, u3.y, u3.z, u3.w};
#pragma unroll
        for (int j = 0; j < 8; ++j) {
            unsigned short hh = f2bf(f0[j]);
            bh0[j] = (short)hh;
            bl0[j] = (short)f2bf(f0[j] - bf2f(hh));
            unsigned short h2 = f2bf(f1[j]);
            bh1[j] = (short)h2;
            bl1[j] = (short)f2bf(f1[j] - bf2f(h2));
        }
    }

    const int rowbase = q * 4;  // C/D: row = (lane>>4)*4 + reg
    float d1 = 3.4e38f, d2 = 3.4e38f;
    int k1 = 0, k2 = 0;

    const unsigned short* pAH = AH + lane * 8;
    const unsigned short* pAL = ALO + lane * 8;

    // ---- prime tile 0's A-fragments ----
    bf16x8 a0h = *(const bf16x8*)(pAH);
    bf16x8 a0l = *(const bf16x8*)(pAL);
    bf16x8 a1h = *(const bf16x8*)(pAH + 512);
    bf16x8 a1l = *(const bf16x8*)(pAL + 512);

#pragma unroll 4
    for (int ct = 0; ct < CT; ++ct) {
        // prefetch next tile (wraps to 0 on last iter; harmless)
        const int nt = (ct + 1) & (CT - 1);
        const bf16x8 n0h = *(const bf16x8*)(pAH + nt * 1024);
        const bf16x8 n0l = *(const bf16x8*)(pAL + nt * 1024);
        const bf16x8 n1h = *(const bf16x8*)(pAH + nt * 1024 + 512);
        const bf16x8 n1l = *(const bf16x8*)(pAL + nt * 1024 + 512);

        const int kb = ct * 16 + rowbase;
        // acc-init with l2e/2: one ds_read_b128 (16 lanes broadcast, free)
        const f32x4 acc_init = *(const f32x4*)&s_l2eh[kb];

        // ---- MFMA cluster: 2 independent 3-chains (R2-validated split) --
        __builtin_amdgcn_s_setprio(1);
        f32x4 a = acc_init;
        a = __builtin_amdgcn_mfma_f32_16x16x32_bf16(a0h, bh0, a, 0, 0, 0);
        a = __builtin_amdgcn_mfma_f32_16x16x32_bf16(a0l, bh0, a, 0, 0, 0);
        a = __builtin_amdgcn_mfma_f32_16x16x32_bf16(a0h, bl0, a, 0, 0, 0);
        f32x4 b = {0.f, 0.f, 0.f, 0.f};
        b = __builtin_amdgcn_mfma_f32_16x16x32_bf16(a1h, bh1, b, 0, 0, 0);
        b = __builtin_amdgcn_mfma_f32_16x16x32_bf16(a1l, bh1, b, 0, 0, 0);
        b = __builtin_amdgcn_mfma_f32_16x16x32_bf16(a1h, bl1, b, 0, 0, 0);
        __builtin_amdgcn_s_setprio(0);

        // ---- top-2 insert (validated med3 form; key = a+b) ----
#pragma unroll
        for (int r = 0; r < 4; ++r) {
            const float d = a[r] + b[r];  // l2e/2 - dot
            const int kk = kb + r;
            const bool c = d < d1, c2 = d < d2;
            const float nd2 = __builtin_amdgcn_fmed3f(d1, d2, d);
            const int nk2 = c2 ? kk : k2;
            k2 = c ? k1 : nk2;
            k1 = c ? kk : k1;
            d2 = nd2;
            d1 = fminf(d1, d);
        }

        a0h = n0h;
        a0l = n0l;
        a1h = n1h;
        a1l = n1l;
    }

    // ---- cross-lane top-2 merge (lanes l, l^16, l^32 share pixel col) ----
    {
        float a1 = d1, a2 = d2;
        int b1 = k1, b2 = k2;
#pragma unroll
        for (int off = 16; off <= 32; off <<= 1) {
            const float od1 = __shfl_xor(a1, off);
            const int ok1 = __shfl_xor(b1, off);
            const float od2 = __shfl_xor(a2, off);
            const int ok2 = __shfl_xor(b2, off);
            const bool c = od1 < a1;
            const float w1 = c ? od1 : a1;
            const int wk1 = c ? ok1 : b1;
            const float l1 = c ? a1 : od1;
            const int lk1 = c ? b1 : ok1;
            const bool cm = od2 < a2;
            const float m2 = cm ? od2 : a2;
            const int mk2 = cm ? ok2 : b2;
            const bool c3 = m2 < l1;
            a2 = c3 ? m2 : l1;
            b2 = c3 ? mk2 : lk1;
            a1 = w1;
            b1 = wk1;
        }
        if (lane < 16) {
            const int pb = wave * 16 + lane;
            s_top[pb][0] = b1;
            s_top[pb][1] = b2;
        }
    }
    __syncthreads();

    // ---- exact refine, pair-parallel: tid<128, 2 threads per pixel, one
    //      candidate each; winner = lexicographic min of (d,k) — identical
    //      tie rule to validated sequential (strict '<', lower idx wins).
    //      One-pass interleaved loads (R3-validated numerics: pairwise-8
    //      l2x identical on both lanes of a pair, strict-serial fma dot).
    if (tid < 2 * PPB) {
        const int pixloc = tid >> 1, which = tid & 1;
        const int pix = blockIdx.x * PPB + pixloc;
        const int k_me = s_top[pixloc][which];
        const float* xr = x_in + (size_t)pix * DIM;
        const float* er = emb + (size_t)k_me * DIM;
        float r[8];
        float acc = 0.f;
#pragma unroll
        for (int i = 0; i < DIM; i += 8) {
            const float4 xa = *(const float4*)(xr + i);
            const float4 xb2 = *(const float4*)(xr + i + 4);
            const float4 ea = *(const float4*)(er + i);
            const float4 eb = *(const float4*)(er + i + 4);
            if (i == 0) {
                r[0] = xa.x * xa.x; r[1] = xa.y * xa.y;
                r[2] = xa.z * xa.z; r[3] = xa.w * xa.w;
                r[4] = xb2.x * xb2.x; r[5] = xb2.y * xb2.y;
                r[6] = xb2.z * xb2.z; r[7] = xb2.w * xb2.w;
            } else {
                r[0] += xa.x * xa.x; r[1] += xa.y * xa.y;
                r[2] += xa.z * xa.z; r[3] += xa.w * xa.w;
                r[4] += xb2.x * xb2.x; r[5] += xb2.y * xb2.y;
                r[6] += xb2.z * xb2.z; r[7] += xb2.w * xb2.w;
            }
            acc = __builtin_fmaf(xa.x, ea.x, acc);
            acc = __builtin_fmaf(xa.y, ea.y, acc);
            acc = __builtin_fmaf(xa.z, ea.z, acc);
            acc = __builtin_fmaf(xa.w, ea.w, acc);
            acc = __builtin_fmaf(xb2.x, eb.x, acc);
            acc = __builtin_fmaf(xb2.y, eb.y, acc);
            acc = __builtin_fmaf(xb2.z, eb.z, acc);
            acc = __builtin_fmaf(xb2.w, eb.w, acc);
        }
        const float l2x = ((r[0] + r[1]) + (r[2] + r[3])) +
                          ((r[4] + r[5]) + (r[6] + r[7]));
        const float d_me = (l2x + s_l2ex[k_me]) - 2.0f * acc;

        const float d_o = __shfl_xor(d_me, 1);
        const int k_o = __shfl_xor(k_me, 1);
        const int sel =
            (d_me < d_o || (d_me == d_o && k_me < k_o)) ? k_me : k_o;
        if (which == 0) {
            s_code[pixloc] = sel;
            codes_out[pix] = (float)sel;
        }
    }
    __syncthreads();

    // ---- coalesced gather: 64 px * 16 float4 = 1024 float4, 4 iters ----
    const float4* emb4 = (const float4*)emb;
    float4* vout4 = (float4*)(vecs_out + (size_t)blockIdx.x * PPB * DIM);
#pragma unroll
    for (int it = 0; it < (PPB * DIM / 4) / BLK; ++it) {
        const int fidx = tid + it * BLK;
        const int pp = fidx >> 4, dd = fidx & 15;
        vout4[fidx] = emb4[(size_t)s_code[pp] * (DIM / 4) + dd];
    }
}

extern "C" void kernel_launch(void* const* d_in, const int* in_sizes, int n_in,
                              void* d_out, int out_size, void* d_ws,
                              size_t ws_size, hipStream_t stream) {
    const float* x_in = (const float*)d_in[0];  // [32,64,64,64] fp32
    const float* emb = (const float*)d_in[1];   // [512,64] fp32

    // workspace layout
    unsigned short* AH = (unsigned short*)d_ws;    // 64 KB (negated hi)
    unsigned short* ALO = AH + NUM_CODES * DIM;    // 64 KB (negated lo)
    float* l2e = (float*)(ALO + NUM_CODES * DIM);  // 2 KB
    float* l2eh = l2e + NUM_CODES;                 // 2 KB

    float* codes_out = (float*)d_out;        // NPIX floats (codes as f32)
    float* vecs_out = (float*)d_out + NPIX;  // NPIX*DIM floats

    hipLaunchKernelGGL(prep_kernel, dim3(32), dim3(256), 0, stream, emb, AH,
                       ALO, l2e, l2eh);
    hipLaunchKernelGGL(vq_main, dim3(NPIX / PPB), dim3(BLK), 0, stream, x_in,
                       AH, ALO, l2e, l2eh, emb, codes_out, vecs_out);
}

// Round 5
// 120.890 us; speedup vs baseline: 3.1471x; 1.0665x over previous
//
#include <hip/hip_runtime.h>

#define NUM_CODES 512
#define DIM 64
#define NPIX (32 * 64 * 64)  // 131072 pixels
#define CT (NUM_CODES / 16)  // 32 code tiles of 16 codes
#define BLK 256
#define NGRP 2               // pixel groups per wave (16 px each) -> 32 px/wave
#define PPB 128              // pixels per block = 4 waves * 32 px

typedef __attribute__((ext_vector_type(8))) short bf16x8;
typedef __attribute__((ext_vector_type(4))) float f32x4;

__device__ __forceinline__ unsigned short f2bf(float f) {
    unsigned u = __float_as_uint(f);
    return (unsigned short)((u + 0x7fffu + ((u >> 16) & 1u)) >> 16);
}
__device__ __forceinline__ float bf2f(unsigned short h) {
    return __uint_as_float(((unsigned)h) << 16);
}

// ---------------------------------------------------------------------------
// Prep: swizzle NEGATED codebook into bf16 hi/lo A-fragment order + exact
// l2e + l2e/2. A-frag (16x16x32): lane = (k_in_32/8)*16 + m, elem j = k%8.
// With -e in A and acc initialized to l2e/2, the MFMA output IS the
// selection key  l2e/2 - dot  directly.
// ---------------------------------------------------------------------------
__global__ __launch_bounds__(256) void prep_kernel(
    const float* __restrict__ emb, unsigned short* __restrict__ AH,
    unsigned short* __restrict__ ALO, float* __restrict__ l2e,
    float* __restrict__ l2eh) {
    const int t = blockIdx.x * 256 + threadIdx.x;  // 0..8191
    const int e0 = t * 4;
    const int c = e0 >> 6, d0 = e0 & 63;
    const float4 v = *(const float4*)(emb + c * DIM + d0);
    float f[4] = {-v.x, -v.y, -v.z, -v.w};  // NEGATED
    unsigned short h[4], l[4];
#pragma unroll
    for (int i = 0; i < 4; ++i) {
        h[i] = f2bf(f[i]);
        l[i] = f2bf(f[i] - bf2f(h[i]));
    }
    const int ct = c >> 4, mr = c & 15, s = d0 >> 5, q = (d0 & 31) >> 3,
              j0 = d0 & 7;
    const int base = ((ct * 2 + s) * 64 + (q * 16 + mr)) * 8 + j0;
    *(ushort4*)(AH + base) = make_ushort4(h[0], h[1], h[2], h[3]);
    *(ushort4*)(ALO + base) = make_ushort4(l[0], l[1], l[2], l[3]);

    if (t < NUM_CODES) {  // exact ||e||^2, validated pairwise-8 order
        const float* e = emb + t * DIM;
        float r[8];
#pragma unroll
        for (int j = 0; j < 8; ++j) {
            float w = e[j];
            r[j] = w * w;
        }
#pragma unroll
        for (int i = 8; i < DIM; i += 8)
#pragma unroll
            for (int j = 0; j < 8; ++j) {
                float w = e[i + j];
                r[j] += w * w;
            }
        float sv =
            ((r[0] + r[1]) + (r[2] + r[3])) + ((r[4] + r[5]) + (r[6] + r[7]));
        l2e[t] = sv;
        l2eh[t] = 0.5f * sv;
    }
}

// ---------------------------------------------------------------------------
// Main: 4 waves / 128 px (R2 structure). NEW vs R2: codebook fragments are
// staged ONCE PER BLOCK into LDS (double-buffered, global_load_lds 16B,
// verified 2-phase template: stage(t+1) -> consume(t) -> vmcnt(0) ->
// s_barrier). This cuts the same-line L2 codebook traffic 4x — the R4
// experiment showed occupancy doesn't help while all CUs hammer the same
// 256 KB of L2 lines; sharing the sweep across the block's 4 waves attacks
// that directly. Insert/merge/refine/gather identical to validated R2.
// ---------------------------------------------------------------------------
__global__ __launch_bounds__(BLK, 4) void vq_main(
    const float* __restrict__ x_in, const unsigned short* __restrict__ AH,
    const unsigned short* __restrict__ ALO, const float* __restrict__ l2e,
    const float* __restrict__ l2eh, const float* __restrict__ emb,
    float* __restrict__ codes_out, float* __restrict__ vecs_out) {
    __shared__ float s_l2eh[NUM_CODES];
    __shared__ float s_l2ex[NUM_CODES];
    __shared__ int s_top[PPB][2];
    __shared__ int s_code[PPB];
    // fragment double-buffer: [parity][4 chunks x 512 shorts] = 2 x 4 KB
    // chunk order = consumer order: {AH.a0, AH.a1, ALO.a0, ALO.a1}
    __shared__ short lbuf[2][2048];

    const int tid = threadIdx.x, lane = tid & 63, wave = tid >> 6;
    s_l2eh[tid] = l2eh[tid];
    s_l2eh[tid + 256] = l2eh[tid + 256];
    s_l2ex[tid] = l2e[tid];
    s_l2ex[tid + 256] = l2e[tid + 256];

    // per-wave staging source: wave w stages chunk w of each tile.
    // tile t chunk bytes: (w<2 ? AH : ALO) + t*2048 + (w&1)*1024, lane*16.
    const char* gsrc_base = (const char*)(wave < 2 ? AH : ALO) +
                            (wave & 1) * 1024 + (size_t)lane * 16;

    // prologue: stage tile 0 into parity 0; full drain via __syncthreads
    __builtin_amdgcn_global_load_lds(
        (const unsigned int*)(gsrc_base),
        (unsigned int*)&lbuf[0][wave * 512], 16, 0, 0);
    __syncthreads();

    const int p = lane & 15, q = lane >> 4;
    const int pw = blockIdx.x * PPB + wave * (16 * NGRP);  // wave's 32 px

    // ---- B fragments for NGRP groups: B[k][n]: n=lane&15, k=(lane>>4)*8+j --
    bf16x8 bh0[NGRP], bl0[NGRP], bh1[NGRP], bl1[NGRP];
#pragma unroll
    for (int g = 0; g < NGRP; ++g) {
        const float* xb = x_in + (size_t)(pw + g * 16 + p) * DIM + q * 8;
        float4 u0 = *(const float4*)(xb);
        float4 u1 = *(const float4*)(xb + 4);
        float4 u2 = *(const float4*)(xb + 32);
        float4 u3 = *(const float4*)(xb + 36);
        float f0[8] = {u0.x, u0.y, u0.z, u0.w, u1.x, u1.y, u1.z, u1.w};
        float f1[8] = {u2.x, u2.y, u2.z, u2.w, u3.x, u3.y, u3.z, u3.w};
#pragma unroll
        for (int j = 0; j < 8; ++j) {
            unsigned short hh = f2bf(f0[j]);
            bh0[g][j] = (short)hh;
            bl0[g][j] = (short)f2bf(f0[j] - bf2f(hh));
            unsigned short h2 = f2bf(f1[j]);
            bh1[g][j] = (short)h2;
            bl1[g][j] = (short)f2bf(f1[j] - bf2f(h2));
        }
    }

    const int rowbase = q * 4;  // C/D: row = (lane>>4)*4 + reg
    float d1[NGRP], d2[NGRP];
    int k1[NGRP], k2[NGRP];
#pragma unroll
    for (int g = 0; g < NGRP; ++g) {
        d1[g] = 3.4e38f;
        d2[g] = 3.4e38f;
        k1[g] = 0;
        k2[g] = 0;
    }

#pragma unroll 2
    for (int ct = 0; ct < CT; ++ct) {
        const int par = ct & 1;
        const int nt = (ct + 1) & (CT - 1);  // wraps on last iter; harmless

        // stage next tile into the other buffer (1 global_load_lds / wave)
        __builtin_amdgcn_global_load_lds(
            (const unsigned int*)(gsrc_base + (size_t)nt * 2048),
            (unsigned int*)&lbuf[par ^ 1][wave * 512], 16, 0, 0);

        // consume current tile from LDS (conflict-free ds_read_b128)
        const bf16x8 a0h = *(const bf16x8*)&lbuf[par][lane * 8];
        const bf16x8 a1h = *(const bf16x8*)&lbuf[par][512 + lane * 8];
        const bf16x8 a0l = *(const bf16x8*)&lbuf[par][1024 + lane * 8];
        const bf16x8 a1l = *(const bf16x8*)&lbuf[par][1536 + lane * 8];

        const int kb = ct * 16 + rowbase;
        const f32x4 acc_init = *(const f32x4*)&s_l2eh[kb];

        // ---- MFMA cluster: 4 independent 3-chains (2 groups x 2 halves) --
        f32x4 accA[NGRP], accB[NGRP];
        __builtin_amdgcn_s_setprio(1);
#pragma unroll
        for (int g = 0; g < NGRP; ++g) {
            f32x4 a = acc_init;
            a = __builtin_amdgcn_mfma_f32_16x16x32_bf16(a0h, bh0[g], a, 0, 0, 0);
            a = __builtin_amdgcn_mfma_f32_16x16x32_bf16(a0l, bh0[g], a, 0, 0, 0);
            a = __builtin_amdgcn_mfma_f32_16x16x32_bf16(a0h, bl0[g], a, 0, 0, 0);
            f32x4 b = {0.f, 0.f, 0.f, 0.f};
            b = __builtin_amdgcn_mfma_f32_16x16x32_bf16(a1h, bh1[g], b, 0, 0, 0);
            b = __builtin_amdgcn_mfma_f32_16x16x32_bf16(a1l, bh1[g], b, 0, 0, 0);
            b = __builtin_amdgcn_mfma_f32_16x16x32_bf16(a1h, bl1[g], b, 0, 0, 0);
            accA[g] = a;
            accB[g] = b;
        }
        __builtin_amdgcn_s_setprio(0);

        // ---- top-2 insert (validated med3 form; key = accA+accB) ----
#pragma unroll
        for (int g = 0; g < NGRP; ++g) {
#pragma unroll
            for (int r = 0; r < 4; ++r) {
                const float d = accA[g][r] + accB[g][r];  // l2e/2 - dot
                const int kk = kb + r;
                const bool c = d < d1[g], c2 = d < d2[g];
                const float nd2 = __builtin_amdgcn_fmed3f(d1[g], d2[g], d);
                const int nk2 = c2 ? kk : k2[g];
                k2[g] = c ? k1[g] : nk2;
                k1[g] = c ? kk : k1[g];
                d2[g] = nd2;
                d1[g] = fminf(d1[g], d);
            }
        }

        // 2-phase handoff: own stage landed, then block-wide barrier.
        asm volatile("s_waitcnt vmcnt(0)" ::: "memory");
        __builtin_amdgcn_s_barrier();
        __builtin_amdgcn_sched_barrier(0);
    }

    // ---- cross-lane top-2 merge (lanes l, l^16, l^32 share pixel col) ----
#pragma unroll
    for (int g = 0; g < NGRP; ++g) {
        float a1 = d1[g], a2 = d2[g];
        int b1 = k1[g], b2 = k2[g];
#pragma unroll
        for (int off = 16; off <= 32; off <<= 1) {
            const float od1 = __shfl_xor(a1, off);
            const int ok1 = __shfl_xor(b1, off);
            const float od2 = __shfl_xor(a2, off);
            const int ok2 = __shfl_xor(b2, off);
            const bool c = od1 < a1;
            const float w1 = c ? od1 : a1;
            const int wk1 = c ? ok1 : b1;
            const float l1 = c ? a1 : od1;
            const int lk1 = c ? b1 : ok1;
            const bool cm = od2 < a2;
            const float m2 = cm ? od2 : a2;
            const int mk2 = cm ? ok2 : b2;
            const bool c3 = m2 < l1;
            a2 = c3 ? m2 : l1;
            b2 = c3 ? mk2 : lk1;
            a1 = w1;
            b1 = wk1;
        }
        if (lane < 16) {
            const int pb = wave * (16 * NGRP) + g * 16 + lane;
            s_top[pb][0] = b1;
            s_top[pb][1] = b2;
        }
    }
    __syncthreads();

    // ---- exact refine, pair-parallel: 2 threads per pixel, one candidate
    //      each; winner = lexicographic min of (d, k) — identical tie rule
    //      to the validated sequential version (strict '<', lower idx wins).
    {
        const int pixloc = tid >> 1, which = tid & 1;  // 256 thr = 2*PPB
        const int pix = blockIdx.x * PPB + pixloc;
        const int k_me = s_top[pixloc][which];
        const float* xr = x_in + (size_t)pix * DIM;
        float x[DIM];
#pragma unroll
        for (int jj = 0; jj < 16; ++jj) {
            const float4 v = *(const float4*)(xr + jj * 4);
            x[4 * jj + 0] = v.x;
            x[4 * jj + 1] = v.y;
            x[4 * jj + 2] = v.z;
            x[4 * jj + 3] = v.w;
        }
        float r[8];
#pragma unroll
        for (int j = 0; j < 8; ++j) r[j] = x[j] * x[j];
#pragma unroll
        for (int i = 8; i < DIM; i += 8)
#pragma unroll
            for (int j = 0; j < 8; ++j) r[j] += x[i + j] * x[i + j];
        const float l2x =
            ((r[0] + r[1]) + (r[2] + r[3])) + ((r[4] + r[5]) + (r[6] + r[7]));

        const float* em = emb + (size_t)k_me * DIM;
        float acc = 0.f;
#pragma unroll
        for (int d = 0; d < DIM; ++d) acc = __builtin_fmaf(x[d], em[d], acc);
        const float d_me = (l2x + s_l2ex[k_me]) - 2.0f * acc;

        const float d_o = __shfl_xor(d_me, 1);
        const int k_o = __shfl_xor(k_me, 1);
        const int sel =
            (d_me < d_o || (d_me == d_o && k_me < k_o)) ? k_me : k_o;
        if (which == 0) {
            s_code[pixloc] = sel;
            codes_out[pix] = (float)sel;
        }
    }
    __syncthreads();

    // ---- coalesced gather: 128 px * 16 float4 = 2048 float4, 8 iters ----
    const float4* emb4 = (const float4*)emb;
    float4* vout4 = (float4*)(vecs_out + (size_t)blockIdx.x * PPB * DIM);
#pragma unroll
    for (int it = 0; it < (PPB * DIM / 4) / BLK; ++it) {
        const int fidx = tid + it * BLK;
        const int pp = fidx >> 4, dd = fidx & 15;
        vout4[fidx] = emb4[(size_t)s_code[pp] * (DIM / 4) + dd];
    }
}

extern "C" void kernel_launch(void* const* d_in, const int* in_sizes, int n_in,
                              void* d_out, int out_size, void* d_ws,
                              size_t ws_size, hipStream_t stream) {
    const float* x_in = (const float*)d_in[0];  // [32,64,64,64] fp32
    const float* emb = (const float*)d_in[1];   // [512,64] fp32

    // workspace layout
    unsigned short* AH = (unsigned short*)d_ws;    // 64 KB (negated hi)
    unsigned short* ALO = AH + NUM_CODES * DIM;    // 64 KB (negated lo)
    float* l2e = (float*)(ALO + NUM_CODES * DIM);  // 2 KB
    float* l2eh = l2e + NUM_CODES;                 // 2 KB

    float* codes_out = (float*)d_out;        // NPIX floats (codes as f32)
    float* vecs_out = (float*)d_out + NPIX;  // NPIX*DIM floats

    hipLaunchKernelGGL(prep_kernel, dim3(32), dim3(256), 0, stream, emb, AH,
                       ALO, l2e, l2eh);
    hipLaunchKernelGGL(vq_main, dim3(NPIX / PPB), dim3(BLK), 0, stream, x_in,
                       AH, ALO, l2e, l2eh, emb, codes_out, vecs_out);
}